// Round 2
// baseline (514.037 us; speedup 1.0000x reference)
//
#include <hip/hip_runtime.h>

// IndRNN: h_t = relu(x_t + w * h_{t-1}), per-channel scan over T.
// T=2048, B=32, H=1024 -> 32768 channels.
//
// R3: same chunked parallel scan as R2 (w >= 0 => step composes in the
// family F(h) = max(m, a + b*h)), but:
//  - NO nontemporal hints (R2 suspect: nt streams measured ~1.7 TB/s at
//    full occupancy vs 6.5 TB/s for plain stores in the same capture)
//  - float4 access (16 B/lane, 1 KB per wave-load) instead of float2
// Pass1: per (chunk, channel) compute (m, a) locally   [parallel over T]
// Pass2: 32-step boundary scan -> h at each chunk start (b = w^64)
// Pass3: per chunk, replay exact recurrence from h_start, write out.

#define T_STEPS 2048
#define B_DIM   32
#define H_DIM   1024
#define BH      (B_DIM * H_DIM)      // 32768 channels
#define BH4     (BH / 4)             // 8192 float4 channel-quads (2^13)
#define NCHUNK  32                   // chunks along T
#define CLEN    (T_STEPS / NCHUNK)   // 64 steps per chunk
#define PF      8                    // prefetch depth (time steps in flight)

typedef float f4 __attribute__((ext_vector_type(4)));

__device__ __forceinline__ f4 step_relu(const f4 w, const f4 h, const f4 x) {
    f4 r;
    r.x = fmaxf(fmaf(w.x, h.x, x.x), 0.f);
    r.y = fmaxf(fmaf(w.y, h.y, x.y), 0.f);
    r.z = fmaxf(fmaf(w.z, h.z, x.z), 0.f);
    r.w = fmaxf(fmaf(w.w, h.w, x.w), 0.f);
    return r;
}

__device__ __forceinline__ f4 step_lin(const f4 w, const f4 a, const f4 x) {
    f4 r;
    r.x = fmaf(w.x, a.x, x.x);
    r.y = fmaf(w.y, a.y, x.y);
    r.z = fmaf(w.z, a.z, x.z);
    r.w = fmaf(w.w, a.w, x.w);
    return r;
}

// ---------- pass 1: per-chunk composed function (m, a) ----------
__global__ __launch_bounds__(256, 4)
void indrnn_pass1(const f4* __restrict__ x, const f4* __restrict__ h0,
                  const f4* __restrict__ w,
                  f4* __restrict__ m_out, f4* __restrict__ a_out)
{
    const int tid = blockIdx.x * 256 + threadIdx.x;   // 0 .. NCHUNK*BH4-1
    const int c   = tid >> 13;                        // chunk id
    const int c4  = tid & (BH4 - 1);                  // channel-quad id
    const f4 wv = w[c4 & (H_DIM / 4 - 1)];

    f4 m, a;
    a.x = a.y = a.z = a.w = 0.f;
    if (c == 0) {                 // chunk 0: seed with h0 -> exact F_0(h0)
        m = h0[c4];
    } else {                      // c>0: incoming h >= 0 (post-relu), so
        m.x = m.y = m.z = m.w = 0.f;  // (m=0, a=0, b=1) acts as identity
    }

    const f4* xp = x + (size_t)c * CLEN * BH4 + c4;

    f4 buf[PF];
#pragma unroll
    for (int i = 0; i < PF; ++i)
        buf[i] = xp[(size_t)i * BH4];

    int t0 = 0;
    for (; t0 + PF < CLEN; t0 += PF) {
        f4 nxt[PF];
#pragma unroll
        for (int i = 0; i < PF; ++i)
            nxt[i] = xp[(size_t)(t0 + PF + i) * BH4];
#pragma unroll
        for (int i = 0; i < PF; ++i) {
            m = step_relu(wv, m, buf[i]);
            a = step_lin(wv, a, buf[i]);
        }
#pragma unroll
        for (int i = 0; i < PF; ++i) buf[i] = nxt[i];
    }
#pragma unroll
    for (int i = 0; i < PF; ++i) {
        m = step_relu(wv, m, buf[i]);
        a = step_lin(wv, a, buf[i]);
    }

    m_out[(size_t)c * BH4 + c4] = m;
    a_out[(size_t)c * BH4 + c4] = a;
}

// ---------- pass 2: boundary scan over chunks ----------
__global__ __launch_bounds__(256, 1)
void indrnn_pass2(const float* __restrict__ h0, const float* __restrict__ w,
                  const float* __restrict__ m, const float* __restrict__ a,
                  float* __restrict__ hstart)
{
    const int ch = blockIdx.x * 256 + threadIdx.x;    // 0..BH-1
    const float wv = w[ch & (H_DIM - 1)];
    float b = wv;
#pragma unroll
    for (int i = 0; i < 6; ++i) b *= b;               // b = w^64

    float mv[NCHUNK], av[NCHUNK];
#pragma unroll
    for (int cc = 0; cc < NCHUNK; ++cc) {             // coalesced prefetch
        mv[cc] = m[cc * BH + ch];
        av[cc] = a[cc * BH + ch];
    }

    float h = h0[ch];
    hstart[ch] = h;                                   // chunk 0 starts at h0
    h = mv[0];                                        // chunk 0 was h0-seeded
    hstart[BH + ch] = h;
#pragma unroll
    for (int cc = 2; cc < NCHUNK; ++cc) {
        h = fmaxf(fmaf(b, h, av[cc - 1]), mv[cc - 1]);
        hstart[cc * BH + ch] = h;
    }
}

// ---------- pass 3: replay exact recurrence per chunk, write out ----------
__global__ __launch_bounds__(256, 4)
void indrnn_pass3(const f4* __restrict__ x, const f4* __restrict__ hstart,
                  const f4* __restrict__ w, f4* __restrict__ out)
{
    const int tid = blockIdx.x * 256 + threadIdx.x;
    const int c   = tid >> 13;
    const int c4  = tid & (BH4 - 1);
    const f4 wv = w[c4 & (H_DIM / 4 - 1)];

    f4 h = hstart[(size_t)c * BH4 + c4];

    const f4* xp = x + (size_t)c * CLEN * BH4 + c4;
    f4* op = out + (size_t)c * CLEN * BH4 + c4;

    f4 buf[PF];
#pragma unroll
    for (int i = 0; i < PF; ++i)
        buf[i] = xp[(size_t)i * BH4];

    int t0 = 0;
    for (; t0 + PF < CLEN; t0 += PF) {
        f4 nxt[PF];
#pragma unroll
        for (int i = 0; i < PF; ++i)
            nxt[i] = xp[(size_t)(t0 + PF + i) * BH4];
#pragma unroll
        for (int i = 0; i < PF; ++i) {
            h = step_relu(wv, h, buf[i]);
            op[(size_t)(t0 + i) * BH4] = h;
        }
#pragma unroll
        for (int i = 0; i < PF; ++i) buf[i] = nxt[i];
    }
#pragma unroll
    for (int i = 0; i < PF; ++i) {
        h = step_relu(wv, h, buf[i]);
        op[(size_t)(t0 + i) * BH4] = h;
    }
}

extern "C" void kernel_launch(void* const* d_in, const int* in_sizes, int n_in,
                              void* d_out, int out_size, void* d_ws, size_t ws_size,
                              hipStream_t stream) {
    const f4* x  = (const f4*)d_in[0];  // (T, B, H)
    const f4* h0 = (const f4*)d_in[1];  // (B, H)
    const f4* w  = (const f4*)d_in[2];  // (H,)
    f4* out = (f4*)d_out;               // (T, B, H)

    // workspace: m | a | hstart, each NCHUNK*BH floats (4 MB) -> 12 MB total
    float* m  = (float*)d_ws;
    float* a  = m + (size_t)NCHUNK * BH;
    float* hs = a + (size_t)NCHUNK * BH;

    indrnn_pass1<<<(NCHUNK * BH4) / 256, 256, 0, stream>>>(
        x, h0, w, (f4*)m, (f4*)a);
    indrnn_pass2<<<BH / 256, 256, 0, stream>>>(
        (const float*)h0, (const float*)w, m, a, hs);
    indrnn_pass3<<<(NCHUNK * BH4) / 256, 256, 0, stream>>>(
        x, (const f4*)hs, w, out);
}